// Round 2
// baseline (801.195 us; speedup 1.0000x reference)
//
#include <hip/hip_runtime.h>

typedef unsigned int u32;

#define NH_   4096
#define NNODE 8192
#define NEDGE 262144

// ---- workspace layout (float offsets) ----
#define OFF_H      0        // 8192*25 = 204800
#define OFF_SC1    204800   // 8192*16 = 131072
#define OFF_NODEH  335872   // 8192*36 = 294912
#define OFF_A      630784   // 8192*42 = 344064
#define OFF_SCALS  974848   // 32*10 = 320
#define OFF_MIDS   975168   // 32*16 = 512
#define OFF_W      975680   // 26284 weights fp32 (padded segments)

// ---- weight offsets inside W (each 16B-aligned) ----
#define W_SC1W   0        // 25x16
#define W_LIN1A  400      // 25x25
#define W_FC1A   1028     // TRANSPOSED: [128][10]
#define W_FC1B   2308     // 128x100
#define W_L2A0   15108    // 25x16
#define W_L2A1   15508    // 25x3
#define W_L2A2   15584    // 25x2
#define W_L2A3   15636    // 25x1
#define W_SC2W   15664    // 10x256
#define W_L1B0   18224    // 10x10
#define W_L1B1   18324    // 3x3
#define W_L1B2   18336    // 2x2
#define W_L1B3   18340    // 1x1
#define W_FC2A   18344    // TRANSPOSED: [128][10]
#define W_FC2B   19624    // 128x16
#define W_LIN2B  21672    // 16x256
#define W_HEADW  25768    // 256x2
#define W_HEADB  26280    // 2
#define W_TOTAL  26284
#define SRC_TOTAL 26267

__device__ __forceinline__ float sigmoidf_(float v) { return 1.0f / (1.0f + __expf(-v)); }

__device__ __forceinline__ float wave_sum(float v) {
#pragma unroll
  for (int m = 32; m > 0; m >>= 1) v += __shfl_xor(v, m);
  return v;
}

struct WPtrs { const float* p[18]; };

// copy all fp32 weights -> contiguous W (fc1_w1/fc2_w1 transposed to [128][10])
__global__ void k_convert(WPtrs wp, float* __restrict__ W) {
  const int soff[19] = {0,400,1025,2305,15105,15505,15580,15630,15655,
                        18215,18315,18324,18328,18329,19609,21657,25753,26265,26267};
  const int dbase[18] = {0,400,1028,2308,15108,15508,15584,15636,15664,
                         18224,18324,18336,18340,18344,19624,21672,25768,26280};
  int t = blockIdx.x * 256 + threadIdx.x;
  if (t >= SRC_TOTAL) return;
  int seg = 0;
  for (int s = 1; s < 18; ++s) seg += (t >= soff[s]) ? 1 : 0;
  int q = t - soff[seg];
  int dst = q;
  if (seg == 2 || seg == 13) {       // fc1_w1 / fc2_w1: (10,128) -> [k][j]
    dst = (q % 128) * 10 + q / 128;
  }
  W[dbase[seg] + dst] = wp.p[seg][q];
}

// per-node: h = x@lin1a/5 (25), sc1 = x@sc1_w/5 (16)
__global__ void __launch_bounds__(256) k_node1(
    const float* __restrict__ wt_x, const float* __restrict__ mt_x,
    const float* __restrict__ W, float* __restrict__ h, float* __restrict__ sc1)
{
  int i = blockIdx.x * 256 + threadIdx.x;
  const float* xp = (i < NH_) ? (wt_x + i * 25) : (mt_x + (i - NH_) * 25);
  float xr[25];
#pragma unroll
  for (int m = 0; m < 25; ++m) xr[m] = xp[m];
  const float* Wl = W + W_LIN1A;
  const float* Ws = W + W_SC1W;
  float ah[25], as[16];
#pragma unroll
  for (int j = 0; j < 25; ++j) ah[j] = 0.f;
#pragma unroll
  for (int j = 0; j < 16; ++j) as[j] = 0.f;
#pragma unroll
  for (int m = 0; m < 25; ++m) {
    float xm = xr[m];
#pragma unroll
    for (int j = 0; j < 25; ++j) ah[j] += xm * Wl[m * 25 + j];
#pragma unroll
    for (int j = 0; j < 16; ++j) as[j] += xm * Ws[m * 16 + j];
  }
#pragma unroll
  for (int j = 0; j < 25; ++j) h[i * 25 + j] = 0.2f * ah[j];
#pragma unroll
  for (int j = 0; j < 16; ++j) sc1[i * 16 + j] = 0.2f * as[j];
}

__device__ __forceinline__ void compute_sh_emb(
    const float* __restrict__ wt_pos, const float* __restrict__ mt_pos,
    int src, int dst, float sh[16], float emb[10])
{
  const float* ps = (src < NH_) ? (wt_pos + src * 3) : (mt_pos + (src - NH_) * 3);
  const float* pd = (dst < NH_) ? (wt_pos + dst * 3) : (mt_pos + (dst - NH_) * 3);
  float vx = ps[0] - pd[0];
  float vy = ps[1] - pd[1];
  float vz = ps[2] - pd[2];
  float d2 = vx * vx + vy * vy + vz * vz;
  float r = sqrtf(d2);
  float rinv = 1.0f / fmaxf(r, 1e-9f);
  float x = vx * rinv, y = vy * rinv, z = vz * rinv;
  float x2 = x * x, y2 = y * y, z2 = z * z;
  float shA = 3.87298334620742f * x * z;             // s15*x*z
  float shB = 1.93649167310371f * (z2 - x2);         // 0.5*s15*(z2-x2)
  sh[0] = 1.f;
  sh[1] = 1.73205080756888f * x;
  sh[2] = 1.73205080756888f * y;
  sh[3] = 1.73205080756888f * z;
  sh[4] = shA;
  sh[5] = 3.87298334620742f * x * y;
  sh[6] = 2.23606797749979f * (y2 - 0.5f * (x2 + z2));
  sh[7] = 3.87298334620742f * y * z;
  sh[8] = shB;
  sh[9]  = 1.08012344973464f * (shA * z + shB * x);
  sh[10] = 2.64575131106459f * shA * y;
  sh[11] = 1.62018517460197f * (4.f * y2 - x2 - z2) * x;
  sh[12] = 1.32287565553230f * y * (2.f * y2 - 3.f * x2 - 3.f * z2);
  sh[13] = 1.62018517460197f * z * (4.f * y2 - x2 - z2);
  sh[14] = 2.64575131106459f * shB * y;
  sh[15] = 1.08012344973464f * (shB * z - shA * x);
  float rb = r * 0.45f;  // r/step, step = 20/9
#pragma unroll
  for (int b = 0; b < 10; ++b) {
    float d = rb - (float)b;
    emb[b] = __expf(-d * d) * 3.16227766016838f;  // *sqrt(10)
  }
}

// edge pass 1: sh/emb -> MLP1 (10->128->100) -> project with l2a* -> atomic into A[dst][42]
__global__ void __launch_bounds__(256) k_edge1(
    const float* __restrict__ wt_pos, const float* __restrict__ mt_pos,
    const int* __restrict__ esrc, const int* __restrict__ edst,
    const float* __restrict__ W, const float* __restrict__ h, float* __restrict__ A)
{
  int e = blockIdx.x * 256 + threadIdx.x;
  int src = esrc[e], dst = edst[e];
  float sh[16], emb[10];
  compute_sh_emb(wt_pos, mt_pos, src, dst, sh, emb);

  const float* W1 = W + W_FC1A;  // [128][10]
  const float* W2 = W + W_FC1B;  // [128][100], rows 16B-aligned
  float acc[100];
#pragma unroll
  for (int c = 0; c < 100; ++c) acc[c] = 0.f;
#pragma unroll 1
  for (int k = 0; k < 128; ++k) {
    const float* w1k = W1 + k * 10;
    float hk = 0.f;
#pragma unroll
    for (int j = 0; j < 10; ++j) hk += emb[j] * w1k[j];
    hk *= 0.31622776601684f;          // /sqrt(10)
    float s = hk * sigmoidf_(hk);     // silu
    const float4* w2r = (const float4*)(W2 + k * 100);
#pragma unroll
    for (int c4 = 0; c4 < 25; ++c4) {
      float4 w = w2r[c4];
      acc[c4 * 4 + 0] += s * w.x;
      acc[c4 * 4 + 1] += s * w.y;
      acc[c4 * 4 + 2] += s * w.z;
      acc[c4 * 4 + 3] += s * w.w;
    }
  }

  const float* hs = h + src * 25;
  float p0[16], p1[3], p2[2], p3 = 0.f;
#pragma unroll
  for (int v = 0; v < 16; ++v) p0[v] = 0.f;
  p1[0] = p1[1] = p1[2] = 0.f; p2[0] = p2[1] = 0.f;
  const float* L0 = W + W_L2A0;
  const float* L1 = W + W_L2A1;
  const float* L2 = W + W_L2A2;
  const float* L3 = W + W_L2A3;
#pragma unroll
  for (int m = 0; m < 25; ++m) {
    float xm = hs[m];
    float t0 = xm * acc[m];
    float t1 = xm * acc[25 + m];
    float t2 = xm * acc[50 + m];
    float t3 = xm * acc[75 + m];
#pragma unroll
    for (int v = 0; v < 16; ++v) p0[v] += t0 * L0[m * 16 + v];
    p1[0] += t1 * L1[m * 3];  p1[1] += t1 * L1[m * 3 + 1];  p1[2] += t1 * L1[m * 3 + 2];
    p2[0] += t2 * L2[m * 2];  p2[1] += t2 * L2[m * 2 + 1];
    p3    += t3 * L3[m];
  }

  const float FS = 0.003125f;  // (1/sqrt(128)) * (1/sqrt(32)) * (1/5)
  float* Ad = A + dst * 42;
#pragma unroll
  for (int v = 0; v < 16; ++v) atomicAdd(Ad + v, p0[v] * FS);
#pragma unroll
  for (int v = 0; v < 3; ++v)
#pragma unroll
    for (int m = 0; m < 3; ++m) atomicAdd(Ad + 16 + v * 3 + m, p1[v] * sh[1 + m] * FS);
#pragma unroll
  for (int v = 0; v < 2; ++v)
#pragma unroll
    for (int m = 0; m < 5; ++m) atomicAdd(Ad + 25 + v * 5 + m, p2[v] * sh[4 + m] * FS);
#pragma unroll
  for (int m = 0; m < 7; ++m) atomicAdd(Ad + 35 + m, p3 * sh[9 + m] * FS);
}

// per-node stage 2: gates/scal -> h0..h3 (36 floats) + group scal sums
__global__ void __launch_bounds__(256) k_node2(
    const float* __restrict__ A, const float* __restrict__ sc1,
    const float* __restrict__ W, float* __restrict__ nodeH, float* __restrict__ scalsum)
{
  int i = blockIdx.x * 256 + threadIdx.x;
  const float* Ai = A + i * 42;
  const float CS_ = 0.38268343236509f, CX_ = 0.92387953251129f;
  float scal[10], gate[6];
#pragma unroll
  for (int c = 0; c < 10; ++c) {
    float s = CS_ * sc1[i * 16 + c] + CX_ * Ai[c];
    scal[c] = s * sigmoidf_(s);
  }
#pragma unroll
  for (int c = 0; c < 6; ++c) {
    float s = CS_ * sc1[i * 16 + 10 + c] + CX_ * Ai[10 + c];
    gate[c] = sigmoidf_(s);
  }
  float* out = nodeH + i * 36;
  const float* B0 = W + W_L1B0;
#pragma unroll
  for (int v = 0; v < 10; ++v) {
    float a = 0.f;
#pragma unroll
    for (int u = 0; u < 10; ++u) a += scal[u] * B0[u * 10 + v];
    out[v] = a * 0.31622776601684f;   // /sqrt(10)
  }
  const float* B1 = W + W_L1B1;
#pragma unroll
  for (int v = 0; v < 3; ++v)
#pragma unroll
    for (int m = 0; m < 3; ++m) {
      float a = 0.f;
#pragma unroll
      for (int u = 0; u < 3; ++u) a += Ai[16 + u * 3 + m] * gate[u] * B1[u * 3 + v];
      out[10 + v * 3 + m] = a * 0.57735026918963f;  // /sqrt(3)
    }
  const float* B2 = W + W_L1B2;
#pragma unroll
  for (int v = 0; v < 2; ++v)
#pragma unroll
    for (int m = 0; m < 5; ++m) {
      float a = 0.f;
#pragma unroll
      for (int u = 0; u < 2; ++u) a += Ai[25 + u * 5 + m] * gate[3 + u] * B2[u * 2 + v];
      out[19 + v * 5 + m] = a * 0.70710678118655f;  // /sqrt(2)
    }
  float b3 = W[W_L1B3];
#pragma unroll
  for (int m = 0; m < 7; ++m) out[29 + m] = Ai[35 + m] * gate[5] * b3;

  // group sums of scal (wave covers 64 consecutive nodes -> single group)
  int g = (i >> 7) & 31;
  int lane = threadIdx.x & 63;
#pragma unroll
  for (int c = 0; c < 10; ++c) {
    float v = wave_sum(scal[c]);
    if (lane == 0) atomicAdd(&scalsum[g * 10 + c], v);
  }
}

// edge pass 2: MLP2 (10->128->16) -> e0..e3 -> group mid sums
__global__ void __launch_bounds__(256) k_edge2(
    const float* __restrict__ wt_pos, const float* __restrict__ mt_pos,
    const int* __restrict__ esrc, const int* __restrict__ edst,
    const float* __restrict__ W, const float* __restrict__ nodeH, float* __restrict__ midsum)
{
  int e = blockIdx.x * 256 + threadIdx.x;
  int src = esrc[e], dst = edst[e];
  float sh[16], emb[10];
  compute_sh_emb(wt_pos, mt_pos, src, dst, sh, emb);

  const float* Wa = W + W_FC2A;  // [128][10]
  const float* Wb = W + W_FC2B;  // [128][16], rows 16B-aligned
  float acc[16];
#pragma unroll
  for (int c = 0; c < 16; ++c) acc[c] = 0.f;
#pragma unroll 1
  for (int k = 0; k < 128; ++k) {
    const float* wak = Wa + k * 10;
    float hk = 0.f;
#pragma unroll
    for (int j = 0; j < 10; ++j) hk += emb[j] * wak[j];
    hk *= 0.31622776601684f;
    float s = hk * sigmoidf_(hk);
    const float4* wbr = (const float4*)(Wb + k * 16);
#pragma unroll
    for (int c4 = 0; c4 < 4; ++c4) {
      float4 w = wbr[c4];
      acc[c4 * 4 + 0] += s * w.x;
      acc[c4 * 4 + 1] += s * w.y;
      acc[c4 * 4 + 2] += s * w.z;
      acc[c4 * 4 + 3] += s * w.w;
    }
  }

  const float* Hs = nodeH + src * 36;
  float ev[16];
#pragma unroll
  for (int c = 0; c < 10; ++c) ev[c] = Hs[c] * acc[c];
#pragma unroll
  for (int u = 0; u < 3; ++u) {
    float d = 0.f;
#pragma unroll
    for (int m = 0; m < 3; ++m) d += Hs[10 + u * 3 + m] * sh[1 + m];
    ev[10 + u] = d * 0.57735026918963f * acc[10 + u];
  }
#pragma unroll
  for (int u = 0; u < 2; ++u) {
    float d = 0.f;
#pragma unroll
    for (int m = 0; m < 5; ++m) d += Hs[19 + u * 5 + m] * sh[4 + m];
    ev[13 + u] = d * 0.44721359549996f * acc[13 + u];
  }
  {
    float d = 0.f;
#pragma unroll
    for (int m = 0; m < 7; ++m) d += Hs[29 + m] * sh[9 + m];
    ev[15] = d * 0.37796447300923f * acc[15];
  }

  // group accumulate: all 64 lanes of a wave share the dst block -> same group
  int g = (dst >> 7) & 31;
  int lane = threadIdx.x & 63;
#pragma unroll
  for (int c = 0; c < 16; ++c) {
    float v = wave_sum(ev[c] * 0.015625f);  // * (1/sqrt(128)) * (1/sqrt(32)) = 1/64
    if (lane == 0) atomicAdd(&midsum[g * 16 + c], v);
  }
}

// finale: fold head through sc2_w / lin2b, one block
__global__ void k_final(const float* __restrict__ W, const float* __restrict__ scalsum,
                        const float* __restrict__ midsum, float* __restrict__ out)
{
  __shared__ float WA[20];  // (10,2) = sc2_w @ head_w
  __shared__ float WB[32];  // (16,2) = lin2b @ head_w
  int t = threadIdx.x;
  const float* S  = W + W_SC2W;
  const float* L  = W + W_LIN2B;
  const float* HW = W + W_HEADW;
  if (t < 20) {
    int j = t >> 1, o = t & 1;
    float a = 0.f;
    for (int c = 0; c < 256; ++c) a += S[j * 256 + c] * HW[c * 2 + o];
    WA[t] = a;
  } else if (t < 52) {
    int q = t - 20, j = q >> 1, o = q & 1;
    float a = 0.f;
    for (int c = 0; c < 256; ++c) a += L[j * 256 + c] * HW[c * 2 + o];
    WB[q] = a;
  }
  __syncthreads();
  if (t < 64) {
    int g = t & 31, o = t >> 5;
    float a = 0.f;
#pragma unroll
    for (int j = 0; j < 10; ++j) a += scalsum[g * 10 + j] * WA[j * 2 + o];
    float b = 0.f;
#pragma unroll
    for (int j = 0; j < 16; ++j) b += midsum[g * 16 + j] * WB[j * 2 + o];
    float y = a * (0.38268343236509f * 0.31622776601684f)   // CS * 1/sqrt(10)
            + b * (0.92387953251129f * 0.25f);              // CX * 1/4
    out[o * 32 + g] = y * (1.0f / 256.0f) + W[W_HEADB + o];
  }
}

extern "C" void kernel_launch(void* const* d_in, const int* in_sizes, int n_in,
                              void* d_out, int out_size, void* d_ws, size_t ws_size,
                              hipStream_t stream)
{
  float* ws = (float*)d_ws;
  const float* wt_pos = (const float*)d_in[0];
  const float* mt_pos = (const float*)d_in[1];
  const float* wt_x   = (const float*)d_in[2];
  const float* mt_x   = (const float*)d_in[3];
  const int* esrc     = (const int*)d_in[6];
  const int* edst     = (const int*)d_in[7];

  float* h       = ws + OFF_H;
  float* sc1     = ws + OFF_SC1;
  float* nodeH   = ws + OFF_NODEH;
  float* A       = ws + OFF_A;
  float* scalsum = ws + OFF_SCALS;
  float* midsum  = ws + OFF_MIDS;
  float* W       = ws + OFF_W;

  // zero accumulators (A + scalsum + midsum are contiguous)
  hipMemsetAsync(A, 0, (size_t)(8192 * 42 + 320 + 512) * sizeof(float), stream);

  WPtrs wp;
  for (int i = 0; i < 18; ++i) wp.p[i] = (const float*)d_in[8 + i];
  k_convert<<<(SRC_TOTAL + 255) / 256, 256, 0, stream>>>(wp, W);
  k_node1<<<NNODE / 256, 256, 0, stream>>>(wt_x, mt_x, W, h, sc1);
  k_edge1<<<NEDGE / 256, 256, 0, stream>>>(wt_pos, mt_pos, esrc, edst, W, h, A);
  k_node2<<<NNODE / 256, 256, 0, stream>>>(A, sc1, W, nodeH, scalsum);
  k_edge2<<<NEDGE / 256, 256, 0, stream>>>(wt_pos, mt_pos, esrc, edst, W, nodeH, midsum);
  k_final<<<1, 256, 0, stream>>>(W, scalsum, midsum, (float*)d_out);
}